// Round 3
// baseline (193.762 us; speedup 1.0000x reference)
//
#include <hip/hip_runtime.h>

#define NUM_CODES 512
#define DIM 64
#define NPIX (32 * 64 * 64)   // 131072 pixels
#define BLK 256
#define PIX_PER_BLK 64        // one pixel per lane
#define NTEAM 4               // one wave per team
#define KPT (NUM_CODES / NTEAM)  // 128 codes per team

// Block = 64 pixels, 4 waves. Wave w scans codes [w*128,(w+1)*128) for all 64
// pixels (one pixel per lane, x[64] in regs, wave-uniform scalar loads of e).
// Numerics of each candidate distance are byte-identical to the validated R1
// kernel; team combine is ascending-k with strict '<' => np.argmin first-min.
__global__ __launch_bounds__(BLK, 4) void vq_kernel(
    const float* __restrict__ x_in, const float* __restrict__ emb,
    float* __restrict__ codes_out, float* __restrict__ vecs_out) {
    __shared__ float s_l2e[NUM_CODES];
    __shared__ float s_best[NTEAM * PIX_PER_BLK];
    __shared__ int s_bi[NTEAM * PIX_PER_BLK];
    __shared__ int s_code[PIX_PER_BLK];

    const int tid = threadIdx.x;

    // ---- phase 0: ||e||^2 for all 512 codes (2 per thread), numpy-pairwise
    // 8-acc order; identical in every block ----
#pragma unroll
    for (int c = 0; c < 2; ++c) {
        const int k = tid + c * BLK;
        const float* e = emb + k * DIM;
        float r[8];
#pragma unroll
        for (int j = 0; j < 8; ++j) {
            float v = e[j];
            r[j] = v * v;
        }
#pragma unroll
        for (int i = 8; i < DIM; i += 8) {
#pragma unroll
            for (int j = 0; j < 8; ++j) {
                float v = e[i + j];
                r[j] += v * v;
            }
        }
        s_l2e[k] =
            ((r[0] + r[1]) + (r[2] + r[3])) + ((r[4] + r[5]) + (r[6] + r[7]));
    }
    __syncthreads();

    // ---- phase 1: per-pixel scan of this team's 128 codes ----
    const int lane = tid & 63;
    const int team = __builtin_amdgcn_readfirstlane(tid >> 6);  // wave-uniform
    const int kbase = team * KPT;
    const int pix = blockIdx.x * PIX_PER_BLK + lane;

    float x[DIM];
    const float4* xp4 = (const float4*)(x_in + (size_t)pix * DIM);
#pragma unroll
    for (int j = 0; j < DIM / 4; ++j) {
        float4 v = xp4[j];
        x[4 * j + 0] = v.x;
        x[4 * j + 1] = v.y;
        x[4 * j + 2] = v.z;
        x[4 * j + 3] = v.w;
    }

    // ||x||^2, numpy-pairwise 8-acc order
    float r[8];
#pragma unroll
    for (int j = 0; j < 8; ++j) r[j] = x[j] * x[j];
#pragma unroll
    for (int i = 8; i < DIM; i += 8) {
#pragma unroll
        for (int j = 0; j < 8; ++j) r[j] += x[i + j] * x[i + j];
    }
    const float l2x =
        ((r[0] + r[1]) + (r[2] + r[3])) + ((r[4] + r[5]) + (r[6] + r[7]));

    float best = 3.4e38f;
    int bi = kbase;
    for (int k = 0; k < KPT; ++k) {
        const float* e = emb + (size_t)(kbase + k) * DIM;  // uniform -> s_load
        float a0 = 0.f, a1 = 0.f, a2 = 0.f, a3 = 0.f;
#pragma unroll
        for (int d = 0; d < DIM; d += 4) {
            a0 = __builtin_fmaf(x[d + 0], e[d + 0], a0);
            a1 = __builtin_fmaf(x[d + 1], e[d + 1], a1);
            a2 = __builtin_fmaf(x[d + 2], e[d + 2], a2);
            a3 = __builtin_fmaf(x[d + 3], e[d + 3], a3);
        }
        const float acc = (a0 + a1) + (a2 + a3);
        const float dist = (l2x + s_l2e[kbase + k]) - 2.0f * acc;
        if (dist < best) {
            best = dist;
            bi = kbase + k;
        }
    }

    // ---- phase 2: combine the 4 team candidates, ascending k, strict '<' ----
    s_best[team * PIX_PER_BLK + lane] = best;
    s_bi[team * PIX_PER_BLK + lane] = bi;
    __syncthreads();
    if (team == 0) {
        float b = s_best[lane];
        int sel = s_bi[lane];
#pragma unroll
        for (int t = 1; t < NTEAM; ++t) {
            const float d = s_best[t * PIX_PER_BLK + lane];
            const int c = s_bi[t * PIX_PER_BLK + lane];
            if (d < b) {
                b = d;
                sel = c;
            }
        }
        s_code[lane] = sel;
        codes_out[pix] = (float)sel;
    }
    __syncthreads();

    // cooperative fully-coalesced gather: 64 pixels * 16 float4 = 1024 float4
    const float4* emb4 = (const float4*)emb;
    float4* vout4 = (float4*)(vecs_out + (size_t)blockIdx.x * PIX_PER_BLK * DIM);
#pragma unroll
    for (int j = 0; j < (PIX_PER_BLK * DIM / 4) / BLK; ++j) {
        const int f = tid + j * BLK;  // [0, 1024)
        const int p = f >> 4;
        const int d4 = f & 15;
        vout4[f] = emb4[(size_t)s_code[p] * (DIM / 4) + d4];
    }
}

extern "C" void kernel_launch(void* const* d_in, const int* in_sizes, int n_in,
                              void* d_out, int out_size, void* d_ws,
                              size_t ws_size, hipStream_t stream) {
    const float* x_in = (const float*)d_in[0];  // [32,64,64,64] fp32
    const float* emb = (const float*)d_in[1];   // [512,64] fp32

    float* codes_out = (float*)d_out;           // NPIX floats (codes as f32)
    float* vecs_out = (float*)d_out + NPIX;     // NPIX*DIM floats

    hipLaunchKernelGGL(vq_kernel, dim3(NPIX / PIX_PER_BLK), dim3(BLK), 0,
                       stream, x_in, emb, codes_out, vecs_out);
}